// Round 5
// baseline (361.500 us; speedup 1.0000x reference)
//
#include <hip/hip_runtime.h>

// MaxUnpooling2D fused gather. B=16, H=W=64, C=256, OH=OW=128.
// mask: per-batch flat int32 index (verified R1).
//
// Structure lesson (R2/R3): the ~165us 1.07GB fillBufferAligned dispatches
// are the harness's 0xAA poison of d_out — inside the timed window, a fixed
// floor. My gather is <162us (absent from top-5); totals 351/366/358 imply
// harness ops ~200us + my kernel ~150us.
//
// R4/R5 theory: output (268MB ~= L3 size) is dirty-poisoned in L3; write-
// allocating stores thrash L3 and evict the just-restored inputs. Use
// NONTEMPORAL stores to stream output to HBM; keep loads cached. 2 quads/
// thread (adjacent w) for 2x MLP; each store = contiguous 1KiB wave span.
// R4 lesson: __builtin_nontemporal_store needs a clang ext_vector_type
// pointer, not HIP's float4 class — use native f32x4.
//
// Gather formulation: max_pool_with_argmax guarantees mask[b,h,w,c] lies in
// its own 2x2 window, same c,b. Output (b,2h+dh,2w+dw,c) has unique source
// updates[b,h,w,c], taken iff mask matches. Every output elem written once;
// no zero-fill pass.

typedef float f32x4 __attribute__((ext_vector_type(4)));

constexpr int B = 16;
constexpr int H = 64, W = 64, C = 256;
constexpr int OW = 2 * W;                               // 128
constexpr int ROW = OW * C;                             // 32768 floats/row
constexpr int OUT_PER_BATCH = (2 * H) * OW * C;         // 2^22
constexpr int N_THREADS = B * H * (W / 2) * (C / 4);    // 2^21 = 2,097,152

__global__ __launch_bounds__(256) void unpool_gather_kernel(
    const float4* __restrict__ updates4,
    const int4*   __restrict__ mask4,
    float*        __restrict__ out) {
    int t = blockIdx.x * blockDim.x + threadIdx.x;      // < 2^21
    // t -> (b, h, w2, c4): thread owns input quads (b,h,2w2,c4),(b,h,2w2+1,c4)
    int c4 = t & 63;
    int w2 = (t >> 6) & 31;
    int h  = (t >> 11) & 63;
    int b  = t >> 17;

    int q0 = ((((b << 6) | h) << 6 | (w2 << 1)) << 6) | c4; // quad (b,h,2w2,c4)
    int q1 = q0 + 64;                                       // (b,h,2w2+1,c4)

    int4   m0 = mask4[q0];
    int4   m1 = mask4[q1];
    float4 u0 = updates4[q0];
    float4 u1 = updates4[q1];

    // flat (2h, 4w2, 4c4) in [OH,OW,C]
    int base0 = ((h << 1) * OW + (w2 << 2)) * C + (c4 << 2);
    float* out_b = out + (long long)b * OUT_PER_BATCH;

    #pragma unroll
    for (int j = 0; j < 4; ++j) {
        int off = ((j >> 1) ? ROW : 0) + ((j & 1) ? C : 0);
        int t0 = base0 + off;          // quad0's window pos (col 4w2 + (j&1))
        int t1 = t0 + 2 * C;           // quad1's window pos (col 4w2+2 + (j&1))
        f32x4 v0, v1;
        v0.x = (m0.x == t0 + 0) ? u0.x : 0.0f;
        v0.y = (m0.y == t0 + 1) ? u0.y : 0.0f;
        v0.z = (m0.z == t0 + 2) ? u0.z : 0.0f;
        v0.w = (m0.w == t0 + 3) ? u0.w : 0.0f;
        v1.x = (m1.x == t1 + 0) ? u1.x : 0.0f;
        v1.y = (m1.y == t1 + 1) ? u1.y : 0.0f;
        v1.z = (m1.z == t1 + 2) ? u1.z : 0.0f;
        v1.w = (m1.w == t1 + 3) ? u1.w : 0.0f;
        __builtin_nontemporal_store(v0, (f32x4*)(out_b + t0));
        __builtin_nontemporal_store(v1, (f32x4*)(out_b + t1));
    }
}

extern "C" void kernel_launch(void* const* d_in, const int* in_sizes, int n_in,
                              void* d_out, int out_size, void* d_ws, size_t ws_size,
                              hipStream_t stream) {
    const float4* updates4 = (const float4*)d_in[0];
    const int4*   mask4    = (const int4*)d_in[1];
    float*        out      = (float*)d_out;

    const int block = 256;
    const int grid  = N_THREADS / block;                // 8192 blocks
    unpool_gather_kernel<<<grid, block, 0, stream>>>(updates4, mask4, out);
}